// Round 8
// baseline (69.193 us; speedup 1.0000x reference)
//
#include <hip/hip_runtime.h>
#include <math.h>

// LinearGating: B=4,S=4096,D=2048,E=64,K=2 -> N=16384 rows
// out (flat f32): [weights N*64][indices N*2 (as float)][logits N*64][probs N*64]
//
// fp16 split-3 MFMA GEMM: C[N x 128] = X[N x 2048] @ [Wg|Wn]
//   x = h + d, w = H + D;  acc1 += h*H ; acc2 += h*(D*2^6) + (d*2^6)*H
//   C = acc1 + acc2 * 2^-6
// R8: all-DMA staging (A as raw fp32 fragment blobs, split done in compute),
// 4 LDS buffers, depth-3 prefetch, ONE barrier/iter with counted vmcnt(10)
// (drain only in the 2-iter tail). 5 uniform gload_lds per wave per iter.

typedef _Float16 f16;
typedef f16  f16x8  __attribute__((ext_vector_type(8)));
typedef float f32x16 __attribute__((ext_vector_type(16)));

constexpr int NROWS = 16384;
constexpr int DDIM  = 2048;
constexpr int NE    = 64;
constexpr int BM    = 32;
constexpr int KI    = 32;            // k per iteration (2 MFMA k-slices)
constexpr int NITER = DDIM / KI;     // 64
constexpr float NSCALE = 1.0f / 4096.0f;

// LDS: 4 buffers x 20 KB = 80 KB
//   A (raw fp32 blobs): buf*20480 + (s*2+j4)*1024          [4 KB]
//   B (f16 blobs):      buf*20480 + 4096 + ((v*4+f)*2+s)*1024 [16 KB]
constexpr int BUFSZ = 20480;
__device__ __forceinline__ int a_off(int buf, int s, int j4) {
    return buf * BUFSZ + (s * 2 + j4) * 1024;
}
__device__ __forceinline__ int b_off(int buf, int v, int f, int s) {
    return buf * BUFSZ + 4096 + ((v * 4 + f) * 2 + s) * 1024;
}

__device__ __forceinline__ float softplus_f(float x) {
    return fmaxf(x, 0.0f) + log1pf(expf(-fabsf(x)));
}

__device__ __forceinline__ void gload_lds16(const void* g, void* l) {
    __builtin_amdgcn_global_load_lds(
        (const __attribute__((address_space(1))) void*)g,
        (__attribute__((address_space(3))) void*)l, 16, 0, 0);
}

// one barrier per iter: batch t landed (vmcnt<=N), my ds_reads drained
#define PIPE_BAR(N) do {                                                   \
    asm volatile("s_waitcnt vmcnt(" #N ") lgkmcnt(0)" ::: "memory");       \
    __builtin_amdgcn_sched_barrier(0);                                     \
    __builtin_amdgcn_s_barrier();                                          \
    __builtin_amdgcn_sched_barrier(0);                                     \
} while (0)

// ---------------- W prep: fragment-ordered fp16 {H, D*2^6} ----------------
// blob(S 0..127, f 0..3, v 0..1): lane l, elem j = Wcat[S*16+(l>>5)*8+j][f*32+(l&31)]
__global__ __launch_bounds__(256) void wprep_kernel(
    const float* __restrict__ Wg, const float* __restrict__ Wn,
    f16* __restrict__ ws)
{
    int t = blockIdx.x * 256 + threadIdx.x;    // 0..32767
    int S = t >> 8;
    int f = (t >> 6) & 3;
    int l = t & 63;
    int k0  = S * 16 + (l >> 5) * 8;
    int col = f * 32 + (l & 31);
    const float* src = (col < NE) ? (Wg + col) : (Wn + col - NE);
    f16x8 hp, lp;
    #pragma unroll
    for (int j = 0; j < 8; ++j) {
        float w  = src[(size_t)(k0 + j) * NE];
        f16 h    = (f16)w;
        float hf = (float)h;
        hp[j] = h;
        lp[j] = (f16)((w - hf) * 64.0f);
    }
    size_t base = (size_t)(S * 4 + f) * 1024;   // f16 units
    *(f16x8*)(ws + base + l * 8)       = hp;
    *(f16x8*)(ws + base + 512 + l * 8) = lp;
}

// ---------------- main fused kernel ----------------
__global__ __launch_bounds__(256, 2) void gemm_gating(
    const float* __restrict__ x, const f16* __restrict__ wfrag,
    const float* __restrict__ noise,
    float* __restrict__ out_w, float* __restrict__ out_idx,
    float* __restrict__ out_logits, float* __restrict__ out_probs)
{
    __shared__ __align__(16) char smem[81920];   // 4 x 20 KB
    const int tid = threadIdx.x;
    const int l   = tid & 63;
    const int w   = tid >> 6;      // wave 0..3; wave tile = 32 rows x cols [w*32, w*32+32)
    const int row0 = blockIdx.x * BM;

    f32x16 acc1, acc2;
    #pragma unroll
    for (int r = 0; r < 16; ++r) { acc1[r] = 0.0f; acc2[r] = 0.0f; }

    // A staging: wave w owns blob (s = w>>1, j4 = w&1).
    // lane L supplies A[row0+(L&31)][t*32 + s*16 + (L>>5)*8 + j4*4 .. +3]
    const float* aSrc = x + (size_t)(row0 + (l & 31)) * DDIM
                          + (w >> 1) * 16 + (l >> 5) * 8 + (w & 1) * 4;
    // B staging: wave w stages col-quad f=w, 4 blobs (v,s) per iter
    const f16* bSrc = wfrag + (size_t)w * 1024 + l * 8;

    auto stage = [&](int t, int buf) {
        gload_lds16(aSrc + (size_t)t * KI, smem + a_off(buf, w >> 1, w & 1));
        #pragma unroll
        for (int v = 0; v < 2; ++v)
            #pragma unroll
            for (int s = 0; s < 2; ++s)
                gload_lds16(bSrc + (size_t)(t * 2 + s) * 4096 + v * 512,
                            smem + b_off(buf, v, w, s));
    };
    auto compute = [&](int buf) {
        #pragma unroll
        for (int s = 0; s < 2; ++s) {
            float4 a0 = *(const float4*)(smem + a_off(buf, s, 0) + l * 16);
            float4 a1 = *(const float4*)(smem + a_off(buf, s, 1) + l * 16);
            float xs[8] = {a0.x, a0.y, a0.z, a0.w, a1.x, a1.y, a1.z, a1.w};
            f16x8 Ah, Al;
            #pragma unroll
            for (int j = 0; j < 8; ++j) {
                f16 h    = (f16)xs[j];
                float hf = (float)h;
                Ah[j] = h;
                Al[j] = (f16)((xs[j] - hf) * 64.0f);
            }
            f16x8 Bh = *(const f16x8*)(smem + b_off(buf, 0, w, s) + l * 16);
            f16x8 Bl = *(const f16x8*)(smem + b_off(buf, 1, w, s) + l * 16);
            acc1 = __builtin_amdgcn_mfma_f32_32x32x16_f16(Ah, Bh, acc1, 0, 0, 0);
            acc2 = __builtin_amdgcn_mfma_f32_32x32x16_f16(Ah, Bl, acc2, 0, 0, 0);
            acc2 = __builtin_amdgcn_mfma_f32_32x32x16_f16(Al, Bh, acc2, 0, 0, 0);
        }
    };

    // -------- prologue: issue batches 0,1,2 (15 DMAs in flight/wave) --------
    stage(0, 0);
    stage(1, 1);
    stage(2, 2);

    // -------- steady loop: one barrier per iter, counted vmcnt --------
    for (int t = 0; t < NITER - 2; ++t) {
        PIPE_BAR(10);                              // batch t landed; t+1,t+2 in flight
        if (t + 3 < NITER) stage(t + 3, (t + 3) & 3);   // into buf freed at t-1
        compute(t & 3);
    }
    PIPE_BAR(5);                                   // batch NITER-2 landed
    compute((NITER - 2) & 3);
    PIPE_BAR(0);                                   // batch NITER-1 landed
    compute((NITER - 1) & 3);
    __syncthreads();   // full drain before smem reuse

    // ---- scatter C to lgf[32][132] (cols 0..63 gate, 64..127 noise) ----
    float* lgf = (float*)smem;
    #pragma unroll
    for (int r = 0; r < 16; ++r) {
        float cv = fmaf(acc2[r], 0.015625f, acc1[r]);
        int row = (r & 3) + 8 * (r >> 2) + 4 * (l >> 5);
        int col = w * 32 + (l & 31);
        lgf[row * 132 + col] = cv;
    }
    __syncthreads();

    // ---- phase1: noise injection -> noisy logits in lgf[:,0..63] + out_logits ----
    {
        const int pr = tid & 31;           // row
        const int c8 = tid >> 5;           // expert chunk of 8 (0..7)
        const int n1 = row0 + pr;
        const float4* gl4 = (const float4*)(lgf + pr * 132 + c8 * 8);
        const float4* nl4 = (const float4*)(lgf + pr * 132 + 64 + c8 * 8);
        const float4* nz4 = (const float4*)(noise + (size_t)n1 * NE + c8 * 8);
        float4* gw4 = (float4*)(lgf + pr * 132 + c8 * 8);
        float4* ol4 = (float4*)(out_logits + (size_t)n1 * NE + c8 * 8);
        #pragma unroll
        for (int q = 0; q < 2; ++q) {
            float4 G = gl4[q], NL = nl4[q], NZ = nz4[q];
            G.x += NZ.x * softplus_f(NL.x) * NSCALE;
            G.y += NZ.y * softplus_f(NL.y) * NSCALE;
            G.z += NZ.z * softplus_f(NL.z) * NSCALE;
            G.w += NZ.w * softplus_f(NL.w) * NSCALE;
            gw4[q] = G;
            ol4[q] = G;
        }
    }
    __syncthreads();

    // ---- phase2: per-row top-2 + softmax; 8 lanes/row x 32 rows ----
    {
        const int g2   = l >> 3;           // row within wave's 8-row group
        const int c    = l & 7;            // expert chunk of 8
        const int row2 = w * 8 + g2;
        const int n2   = row0 + row2;

        float mv[8];
        {
            const float4* mr = (const float4*)(lgf + row2 * 132 + c * 8);
            float4 m0 = mr[0], m1 = mr[1];
            mv[0]=m0.x; mv[1]=m0.y; mv[2]=m0.z; mv[3]=m0.w;
            mv[4]=m1.x; mv[5]=m1.y; mv[6]=m1.z; mv[7]=m1.w;
        }
        float v0 = -INFINITY, v1 = -INFINITY;
        int i0 = 0, i1 = 0;
        #pragma unroll
        for (int j = 0; j < 8; ++j) {
            float v = mv[j]; int e = c * 8 + j;
            if (v > v0) { v1 = v0; i1 = i0; v0 = v; i0 = e; }
            else if (v > v1) { v1 = v; i1 = e; }
        }
        #pragma unroll
        for (int m = 1; m <= 4; m <<= 1) {
            float ov0 = __shfl_xor(v0, m), ov1 = __shfl_xor(v1, m);
            int   oi0 = __shfl_xor(i0, m), oi1 = __shfl_xor(i1, m);
            if (ov0 > v0) {
                bool keep = (v0 > ov1);
                v1 = keep ? v0 : ov1; i1 = keep ? i0 : oi1;
                v0 = ov0; i0 = oi0;
            } else if (ov0 > v1) {
                v1 = ov0; i1 = oi0;
            }
        }
        const int srcl = l & 56;
        v0 = __shfl(v0, srcl); i0 = __shfl(i0, srcl);
        v1 = __shfl(v1, srcl); i1 = __shfl(i1, srcl);

        float se = 0.0f;
        #pragma unroll
        for (int j = 0; j < 8; ++j) se += expf(mv[j] - v0);
        se += __shfl_xor(se, 1); se += __shfl_xor(se, 2); se += __shfl_xor(se, 4);
        float inv_se = 1.0f / se;

        float t  = expf(v1 - v0);
        float w0 = 1.0f / (1.0f + t);
        float w1 = t * w0;

        float pr[8], wt[8];
        #pragma unroll
        for (int j = 0; j < 8; ++j) {
            int e = c * 8 + j;
            pr[j] = expf(mv[j] - v0) * inv_se;
            wt[j] = (e == i0) ? w0 : ((e == i1) ? w1 : 0.0f);
        }
        *(float4*)(out_probs + (size_t)n2 * NE + c * 8)     = make_float4(pr[0], pr[1], pr[2], pr[3]);
        *(float4*)(out_probs + (size_t)n2 * NE + c * 8 + 4) = make_float4(pr[4], pr[5], pr[6], pr[7]);
        *(float4*)(out_w + (size_t)n2 * NE + c * 8)         = make_float4(wt[0], wt[1], wt[2], wt[3]);
        *(float4*)(out_w + (size_t)n2 * NE + c * 8 + 4)     = make_float4(wt[4], wt[5], wt[6], wt[7]);
        if (c == 0) {
            *(float2*)(out_idx + (size_t)n2 * 2) = make_float2((float)i0, (float)i1);
        }
    }
}

extern "C" void kernel_launch(void* const* d_in, const int* in_sizes, int n_in,
                              void* d_out, int out_size, void* d_ws, size_t ws_size,
                              hipStream_t stream) {
    (void)in_sizes; (void)n_in; (void)ws_size; (void)out_size;
    const float* x     = (const float*)d_in[0];
    const float* Wg    = (const float*)d_in[1];
    const float* Wn    = (const float*)d_in[2];
    const float* noise = (const float*)d_in[3];
    float* out        = (float*)d_out;
    float* out_w      = out;
    float* out_idx    = out + (size_t)NROWS * NE;
    float* out_logits = out_idx + (size_t)NROWS * 2;
    float* out_probs  = out_logits + (size_t)NROWS * NE;
    f16* wfrag = (f16*)d_ws;   // 1 MB

    wprep_kernel<<<128, 256, 0, stream>>>(Wg, Wn, wfrag);
    gemm_gating<<<NROWS / BM, 256, 0, stream>>>(
        x, wfrag, noise, out_w, out_idx, out_logits, out_probs);
}

// Round 9
// 56.977 us; speedup vs baseline: 1.2144x; 1.2144x over previous
//
#include <hip/hip_runtime.h>
#include <math.h>

// LinearGating: B=4,S=4096,D=2048,E=64,K=2 -> N=16384 rows
// out (flat f32): [weights N*64][indices N*2 (as float)][logits N*64][probs N*64]
//
// fp16 split-3 MFMA GEMM: C[N x 128] = X[N x 2048] @ [Wg|Wn]
//   x = h + d, w = H + D;  acc1 += h*H ; acc2 += h*(D*2^6) + (d*2^6)*H
//   C = acc1 + acc2 * 2^-6
// R9: 512-thr blocks, 8 waves = 2 K-halves x 4 col-quads (K-split in block,
// NITER=32 each). A: raw-fp32 DMA blobs, 4 buffers, depth-3, counted vmcnt.
// B: wave-private, global->reg double-buffered (no LDS). One barrier/iter.
// 16 waves/CU (4/SIMD) for latency hiding; LDS merge of K-halves at end.

typedef _Float16 f16;
typedef f16  f16x8  __attribute__((ext_vector_type(8)));
typedef float f32x16 __attribute__((ext_vector_type(16)));

constexpr int NROWS = 16384;
constexpr int DDIM  = 2048;
constexpr int NE    = 64;
constexpr int BM    = 32;
constexpr int KI    = 32;                 // k per iteration per half
constexpr int NITER = 1024 / KI;          // 32
constexpr float NSCALE = 1.0f / 4096.0f;

// LDS: A bufs [0,32K): buf(4) x half(2) x s(2) x j4(2) x 1KB
//      merge mg [32K,48K): [32][128] f32
//      lgf reuses [0,16896) after k-loop drain
__device__ __forceinline__ int a_off(int buf, int h, int s, int j4) {
    return (((buf * 2 + h) * 2 + s) * 2 + j4) * 1024;
}

__device__ __forceinline__ float softplus_f(float x) {
    return fmaxf(x, 0.0f) + log1pf(expf(-fabsf(x)));
}

__device__ __forceinline__ void gload_lds16(const void* g, void* l) {
    __builtin_amdgcn_global_load_lds(
        (const __attribute__((address_space(1))) void*)g,
        (__attribute__((address_space(3))) void*)l, 16, 0, 0);
}

#define PIPE_BAR(N) do {                                                   \
    asm volatile("s_waitcnt vmcnt(" #N ") lgkmcnt(0)" ::: "memory");       \
    __builtin_amdgcn_sched_barrier(0);                                     \
    __builtin_amdgcn_s_barrier();                                          \
    __builtin_amdgcn_sched_barrier(0);                                     \
} while (0)

// ---------------- W prep: fragment-ordered fp16 {H, D*2^6} ----------------
// blob(S 0..127, f 0..3, v 0..1): lane l, elem j = Wcat[S*16+(l>>5)*8+j][f*32+(l&31)]
__global__ __launch_bounds__(256) void wprep_kernel(
    const float* __restrict__ Wg, const float* __restrict__ Wn,
    f16* __restrict__ ws)
{
    int t = blockIdx.x * 256 + threadIdx.x;    // 0..32767
    int S = t >> 8;
    int f = (t >> 6) & 3;
    int l = t & 63;
    int k0  = S * 16 + (l >> 5) * 8;
    int col = f * 32 + (l & 31);
    const float* src = (col < NE) ? (Wg + col) : (Wn + col - NE);
    f16x8 hp, lp;
    #pragma unroll
    for (int j = 0; j < 8; ++j) {
        float w  = src[(size_t)(k0 + j) * NE];
        f16 h    = (f16)w;
        float hf = (float)h;
        hp[j] = h;
        lp[j] = (f16)((w - hf) * 64.0f);
    }
    size_t base = (size_t)(S * 4 + f) * 1024;   // f16 units
    *(f16x8*)(ws + base + l * 8)       = hp;
    *(f16x8*)(ws + base + 512 + l * 8) = lp;
}

// ---------------- main fused kernel ----------------
__global__ __launch_bounds__(512, 4) void gemm_gating(
    const float* __restrict__ x, const f16* __restrict__ wfrag,
    const float* __restrict__ noise,
    float* __restrict__ out_w, float* __restrict__ out_idx,
    float* __restrict__ out_logits, float* __restrict__ out_probs)
{
    __shared__ __align__(16) char smem[49152];
    const int tid = threadIdx.x;
    const int l   = tid & 63;
    const int w   = tid >> 6;      // 0..7
    const int h   = w >> 2;        // k-half
    const int f   = w & 3;         // col quad (cols f*32..+31)
    const int row0 = blockIdx.x * BM;

    f32x16 acc1, acc2;
    #pragma unroll
    for (int r = 0; r < 16; ++r) { acc1[r] = 0.0f; acc2[r] = 0.0f; }

    // --- A staging: wave w owns blob (sh = w&1? ...) pick bijection:
    //     stage blob (h_s = w>>2, s_s = (w>>1)&1, j4_s = w&1)
    const int h_s  = w >> 2, s_s = (w >> 1) & 1, j4_s = w & 1;
    const float* aSrc = x + (size_t)(row0 + (l & 31)) * DDIM
                          + h_s * 1024 + s_s * 16 + (l >> 5) * 8 + j4_s * 4;
    auto stageA = [&](int t, int buf) {
        gload_lds16(aSrc + (size_t)t * KI, smem + a_off(buf, h_s, s_s, j4_s));
    };

    // --- B: wave-private, global->reg. Slice S = h*64 + t*2 + s ---
    const f16* bBase = wfrag + (size_t)f * 1024 + l * 8;   // + S*4096 per slice
    f16x8 bh0c, bl0c, bh1c, bl1c;       // current iter
    f16x8 bh0n, bl0n, bh1n, bl1n;       // next iter
    auto loadB = [&](int t, f16x8& H0, f16x8& L0, f16x8& H1, f16x8& L1) {
        const f16* p = bBase + (size_t)(h * 64 + t * 2) * 4096;
        H0 = *(const f16x8*)p;
        L0 = *(const f16x8*)(p + 512);
        H1 = *(const f16x8*)(p + 4096);
        L1 = *(const f16x8*)(p + 4096 + 512);
    };

    auto compute = [&](int buf) {
        #pragma unroll
        for (int s = 0; s < 2; ++s) {
            float4 a0 = *(const float4*)(smem + a_off(buf, h, s, 0) + l * 16);
            float4 a1 = *(const float4*)(smem + a_off(buf, h, s, 1) + l * 16);
            float xs[8] = {a0.x, a0.y, a0.z, a0.w, a1.x, a1.y, a1.z, a1.w};
            f16x8 Ah, Al;
            #pragma unroll
            for (int j = 0; j < 8; ++j) {
                f16 hh   = (f16)xs[j];
                float hf = (float)hh;
                Ah[j] = hh;
                Al[j] = (f16)((xs[j] - hf) * 64.0f);
            }
            f16x8 Bh = s ? bh1c : bh0c;
            f16x8 Bl = s ? bl1c : bl0c;
            acc1 = __builtin_amdgcn_mfma_f32_32x32x16_f16(Ah, Bh, acc1, 0, 0, 0);
            acc2 = __builtin_amdgcn_mfma_f32_32x32x16_f16(Ah, Bl, acc2, 0, 0, 0);
            acc2 = __builtin_amdgcn_mfma_f32_32x32x16_f16(Al, Bh, acc2, 0, 0, 0);
        }
    };

    // -------- prologue: A(0), B(0), A(1), A(2) --------
    stageA(0, 0);
    loadB(0, bh0c, bl0c, bh1c, bl1c);
    stageA(1, 1);
    stageA(2, 2);

    // iter 0 (special wait: allow A1,A2,B1,A3 = 7)
    loadB(1, bh0n, bl0n, bh1n, bl1n);
    stageA(3, 3);
    PIPE_BAR(7);
    compute(0);
    bh0c = bh0n; bl0c = bl0n; bh1c = bh1n; bl1c = bl1n;

    // steady: t = 1 .. NITER-4
    for (int t = 1; t < NITER - 3; ++t) {
        loadB(t + 1, bh0n, bl0n, bh1n, bl1n);
        stageA(t + 3, (t + 3) & 3);
        PIPE_BAR(6);
        compute(t & 3);
        bh0c = bh0n; bl0c = bl0n; bh1c = bh1n; bl1c = bl1n;
    }
    // tails
    {
        int t = NITER - 3;
        loadB(t + 1, bh0n, bl0n, bh1n, bl1n);
        PIPE_BAR(5);
        compute(t & 3);
        bh0c = bh0n; bl0c = bl0n; bh1c = bh1n; bl1c = bl1n;
    }
    {
        int t = NITER - 2;
        loadB(t + 1, bh0n, bl0n, bh1n, bl1n);
        PIPE_BAR(4);
        compute(t & 3);
        bh0c = bh0n; bl0c = bl0n; bh1c = bh1n; bl1c = bl1n;
    }
    PIPE_BAR(0);
    compute((NITER - 1) & 3);
    __syncthreads();

    // ---- merge K-halves: h=1 waves write partial, h=0 adds ----
    float* mg  = (float*)(smem + 32768);   // [32][128]
    if (h == 1) {
        #pragma unroll
        for (int r = 0; r < 16; ++r) {
            float cv = fmaf(acc2[r], 0.015625f, acc1[r]);
            int row = (r & 3) + 8 * (r >> 2) + 4 * (l >> 5);
            int col = f * 32 + (l & 31);
            mg[row * 128 + col] = cv;
        }
    }
    __syncthreads();

    float* lgf = (float*)smem;             // [32][132]
    if (h == 0) {
        #pragma unroll
        for (int r = 0; r < 16; ++r) {
            float cv = fmaf(acc2[r], 0.015625f, acc1[r]);
            int row = (r & 3) + 8 * (r >> 2) + 4 * (l >> 5);
            int col = f * 32 + (l & 31);
            lgf[row * 132 + col] = cv + mg[row * 128 + col];
        }
    }
    __syncthreads();

    // ---- phase1: noise injection; 512 thr = 32 rows x 16 col-quads ----
    {
        const int pr = tid & 31;           // row
        const int c4 = tid >> 5;           // float4 chunk 0..15 (cols c4*4)
        const int n1 = row0 + pr;
        float4 G  = *(const float4*)(lgf + pr * 132 + c4 * 4);
        float4 NL = *(const float4*)(lgf + pr * 132 + 64 + c4 * 4);
        float4 NZ = *(const float4*)(noise + (size_t)n1 * NE + c4 * 4);
        G.x += NZ.x * softplus_f(NL.x) * NSCALE;
        G.y += NZ.y * softplus_f(NL.y) * NSCALE;
        G.z += NZ.z * softplus_f(NL.z) * NSCALE;
        G.w += NZ.w * softplus_f(NL.w) * NSCALE;
        *(float4*)(lgf + pr * 132 + c4 * 4) = G;
        *(float4*)(out_logits + (size_t)n1 * NE + c4 * 4) = G;
    }
    __syncthreads();

    // ---- phase2: per-row top-2 + softmax; waves 0..3, 8 lanes/row ----
    if (w < 4) {
        const int g2   = l >> 3;           // row within wave's 8-row group
        const int c    = l & 7;            // expert chunk of 8
        const int row2 = w * 8 + g2;
        const int n2   = row0 + row2;

        float mv[8];
        {
            const float4* mr = (const float4*)(lgf + row2 * 132 + c * 8);
            float4 m0 = mr[0], m1 = mr[1];
            mv[0]=m0.x; mv[1]=m0.y; mv[2]=m0.z; mv[3]=m0.w;
            mv[4]=m1.x; mv[5]=m1.y; mv[6]=m1.z; mv[7]=m1.w;
        }
        float v0 = -INFINITY, v1 = -INFINITY;
        int i0 = 0, i1 = 0;
        #pragma unroll
        for (int j = 0; j < 8; ++j) {
            float v = mv[j]; int e = c * 8 + j;
            if (v > v0) { v1 = v0; i1 = i0; v0 = v; i0 = e; }
            else if (v > v1) { v1 = v; i1 = e; }
        }
        #pragma unroll
        for (int m = 1; m <= 4; m <<= 1) {
            float ov0 = __shfl_xor(v0, m), ov1 = __shfl_xor(v1, m);
            int   oi0 = __shfl_xor(i0, m), oi1 = __shfl_xor(i1, m);
            if (ov0 > v0) {
                bool keep = (v0 > ov1);
                v1 = keep ? v0 : ov1; i1 = keep ? i0 : oi1;
                v0 = ov0; i0 = oi0;
            } else if (ov0 > v1) {
                v1 = ov0; i1 = oi0;
            }
        }
        const int srcl = l & 56;
        v0 = __shfl(v0, srcl); i0 = __shfl(i0, srcl);
        v1 = __shfl(v1, srcl); i1 = __shfl(i1, srcl);

        float se = 0.0f;
        #pragma unroll
        for (int j = 0; j < 8; ++j) se += expf(mv[j] - v0);
        se += __shfl_xor(se, 1); se += __shfl_xor(se, 2); se += __shfl_xor(se, 4);
        float inv_se = 1.0f / se;

        float t  = expf(v1 - v0);
        float w0 = 1.0f / (1.0f + t);
        float w1 = t * w0;

        float pr[8], wt[8];
        #pragma unroll
        for (int j = 0; j < 8; ++j) {
            int e = c * 8 + j;
            pr[j] = expf(mv[j] - v0) * inv_se;
            wt[j] = (e == i0) ? w0 : ((e == i1) ? w1 : 0.0f);
        }
        *(float4*)(out_probs + (size_t)n2 * NE + c * 8)     = make_float4(pr[0], pr[1], pr[2], pr[3]);
        *(float4*)(out_probs + (size_t)n2 * NE + c * 8 + 4) = make_float4(pr[4], pr[5], pr[6], pr[7]);
        *(float4*)(out_w + (size_t)n2 * NE + c * 8)         = make_float4(wt[0], wt[1], wt[2], wt[3]);
        *(float4*)(out_w + (size_t)n2 * NE + c * 8 + 4)     = make_float4(wt[4], wt[5], wt[6], wt[7]);
        if (c == 0) {
            *(float2*)(out_idx + (size_t)n2 * 2) = make_float2((float)i0, (float)i1);
        }
    }
}

extern "C" void kernel_launch(void* const* d_in, const int* in_sizes, int n_in,
                              void* d_out, int out_size, void* d_ws, size_t ws_size,
                              hipStream_t stream) {
    (void)in_sizes; (void)n_in; (void)ws_size; (void)out_size;
    const float* x     = (const float*)d_in[0];
    const float* Wg    = (const float*)d_in[1];
    const float* Wn    = (const float*)d_in[2];
    const float* noise = (const float*)d_in[3];
    float* out        = (float*)d_out;
    float* out_w      = out;
    float* out_idx    = out + (size_t)NROWS * NE;
    float* out_logits = out_idx + (size_t)NROWS * 2;
    float* out_probs  = out_logits + (size_t)NROWS * NE;
    f16* wfrag = (f16*)d_ws;   // 1 MB

    wprep_kernel<<<128, 256, 0, stream>>>(Wg, Wn, wfrag);
    gemm_gating<<<NROWS / BM, 512, 0, stream>>>(
        x, wfrag, noise, out_w, out_idx, out_logits, out_probs);
}

// Round 10
// 56.083 us; speedup vs baseline: 1.2338x; 1.0159x over previous
//
#include <hip/hip_runtime.h>
#include <math.h>

// LinearGating: B=4,S=4096,D=2048,E=64,K=2 -> N=16384 rows
// out (flat f32): [weights N*64][indices N*2 (as float)][logits N*64][probs N*64]
//
// fp16 split-3 MFMA GEMM: C[N x 128] = X[N x 2048] @ [Wg|Wn]
//   x = h + d, w = H + D;  acc1 += h*H ; acc2 += h*(D*2^6) + (d*2^6)*H
//   C = acc1 + acc2 * 2^-6
// R10: conversion moved to staging, done ONCE (8 waves x 4 el/iter), written
// as ready f16 blobs via ds_write (no global_load_lds). All VMEM deps are
// register-tracked -> barrier is lgkmcnt(0)+s_barrier only; compiler emits
// counted vmcnt. A-regs slack 2 iters (4 LDS bufs), B-regs slack 1.
// compute() = 4 ds_read_b128 + 6 MFMA, zero VALU.

typedef _Float16 f16;
typedef f16  f16x4  __attribute__((ext_vector_type(4)));
typedef f16  f16x8  __attribute__((ext_vector_type(8)));
typedef float f32x16 __attribute__((ext_vector_type(16)));

constexpr int NROWS = 16384;
constexpr int DDIM  = 2048;
constexpr int NE    = 64;
constexpr int BM    = 32;
constexpr int KI    = 32;                 // k per iteration per half
constexpr int NITER = 1024 / KI;          // 32
constexpr float NSCALE = 1.0f / 4096.0f;

// LDS: A f16 blobs [0,32K): buf(4) x half(2) x s(2) x v(2) x 1KB
//      merge mg [32K,48K): [32][128] f32 ; lgf reuses [0,16896) at end
__device__ __forceinline__ int a_off(int buf, int h, int s, int v) {
    return (((buf * 2 + h) * 2 + s) * 2 + v) * 1024;
}

__device__ __forceinline__ float softplus_f(float x) {
    return fmaxf(x, 0.0f) + log1pf(expf(-fabsf(x)));
}

// barrier: only LDS ordering; VMEM deps are register-tracked by compiler
__device__ __forceinline__ void tile_bar() {
    asm volatile("s_waitcnt lgkmcnt(0)" ::: "memory");
    __builtin_amdgcn_sched_barrier(0);
    __builtin_amdgcn_s_barrier();
    __builtin_amdgcn_sched_barrier(0);
}

// ---------------- W prep: fragment-ordered fp16 {H, D*2^6} ----------------
// blob(S 0..127, f 0..3, v 0..1): lane l, elem j = Wcat[S*16+(l>>5)*8+j][f*32+(l&31)]
__global__ __launch_bounds__(256) void wprep_kernel(
    const float* __restrict__ Wg, const float* __restrict__ Wn,
    f16* __restrict__ ws)
{
    int t = blockIdx.x * 256 + threadIdx.x;    // 0..32767
    int S = t >> 8;
    int f = (t >> 6) & 3;
    int l = t & 63;
    int k0  = S * 16 + (l >> 5) * 8;
    int col = f * 32 + (l & 31);
    const float* src = (col < NE) ? (Wg + col) : (Wn + col - NE);
    f16x8 hp, lp;
    #pragma unroll
    for (int j = 0; j < 8; ++j) {
        float w  = src[(size_t)(k0 + j) * NE];
        f16 h    = (f16)w;
        float hf = (float)h;
        hp[j] = h;
        lp[j] = (f16)((w - hf) * 64.0f);
    }
    size_t base = (size_t)(S * 4 + f) * 1024;   // f16 units
    *(f16x8*)(ws + base + l * 8)       = hp;
    *(f16x8*)(ws + base + 512 + l * 8) = lp;
}

// ---------------- main fused kernel ----------------
__global__ __launch_bounds__(512, 4) void gemm_gating(
    const float* __restrict__ x, const f16* __restrict__ wfrag,
    const float* __restrict__ noise,
    float* __restrict__ out_w, float* __restrict__ out_idx,
    float* __restrict__ out_logits, float* __restrict__ out_probs)
{
    __shared__ __align__(16) char smem[49152];
    const int tid = threadIdx.x;
    const int l   = tid & 63;
    const int w   = tid >> 6;      // 0..7
    const int h   = w >> 2;        // compute: k-half
    const int f   = w & 3;         // compute: col quad (cols f*32..+31)
    const int row0 = blockIdx.x * BM;

    f32x16 acc1, acc2;
    #pragma unroll
    for (int r = 0; r < 16; ++r) { acc1[r] = 0.0f; acc2[r] = 0.0f; }

    // --- A staging role: wave w owns (h_s = w>>2, s_s = (w>>1)&1, j4 = w&1) ---
    // lane l loads x[row0+(l&31)][t*32 + h_s*1024 + s_s*16 + (l>>5)*8 + j4*4 ..+3]
    const int h_s = w >> 2, s_s = (w >> 1) & 1, j4 = w & 1;
    const float* aSrc = x + (size_t)(row0 + (l & 31)) * DDIM
                          + h_s * 1024 + s_s * 16 + (l >> 5) * 8 + j4 * 4;
    auto loadA = [&](int t) -> float4 {
        return *(const float4*)(aSrc + (size_t)t * KI);
    };
    // convert 4 elements -> hi/lo f16x4, write both blobs (tile tt)
    auto cvtWrite = [&](float4 xv, int tt) {
        int buf = tt & 3;
        float xs[4] = {xv.x, xv.y, xv.z, xv.w};
        f16x4 hi, lo;
        #pragma unroll
        for (int j = 0; j < 4; ++j) {
            f16 hh   = (f16)xs[j];
            float hf = (float)hh;
            hi[j] = hh;
            lo[j] = (f16)((xs[j] - hf) * 64.0f);
        }
        *(f16x4*)(smem + a_off(buf, h_s, s_s, 0) + l * 16 + j4 * 8) = hi;
        *(f16x4*)(smem + a_off(buf, h_s, s_s, 1) + l * 16 + j4 * 8) = lo;
    };

    // --- B: wave-private, global->reg, double-buffered. Slice S = h*64+t*2+s ---
    const f16* bBase = wfrag + (size_t)f * 1024 + l * 8;
    f16x8 bh0c, bl0c, bh1c, bl1c, bh0n, bl0n, bh1n, bl1n;
    auto loadB = [&](int t, f16x8& H0, f16x8& L0, f16x8& H1, f16x8& L1) {
        const f16* p = bBase + (size_t)(h * 64 + t * 2) * 4096;
        H0 = *(const f16x8*)p;
        L0 = *(const f16x8*)(p + 512);
        H1 = *(const f16x8*)(p + 4096);
        L1 = *(const f16x8*)(p + 4096 + 512);
    };

    auto compute = [&](int t) {
        int buf = t & 3;
        #pragma unroll
        for (int s = 0; s < 2; ++s) {
            f16x8 Ah = *(const f16x8*)(smem + a_off(buf, h, s, 0) + l * 16);
            f16x8 Al = *(const f16x8*)(smem + a_off(buf, h, s, 1) + l * 16);
            f16x8 Bh = s ? bh1c : bh0c;
            f16x8 Bl = s ? bl1c : bl0c;
            acc1 = __builtin_amdgcn_mfma_f32_32x32x16_f16(Ah, Bh, acc1, 0, 0, 0);
            acc2 = __builtin_amdgcn_mfma_f32_32x32x16_f16(Ah, Bl, acc2, 0, 0, 0);
            acc2 = __builtin_amdgcn_mfma_f32_32x32x16_f16(Al, Bh, acc2, 0, 0, 0);
        }
    };

    // -------- prologue: tiles 0,1 staged; A(2),A(3) in flight; B(0) loaded --------
    float4 r0 = loadA(0);
    float4 r1 = loadA(1);
    loadB(0, bh0c, bl0c, bh1c, bl1c);
    float4 sc = loadA(2);          // slot c: converted at iter 0
    float4 sm = loadA(3);          // slot m
    cvtWrite(r0, 0);
    cvtWrite(r1, 1);

    for (int t = 0; t < NITER; ++t) {
        tile_bar();                               // tile t blobs visible
        float4 sn = sc;
        if (t + 4 < NITER) sn = loadA(t + 4);     // issue depth-4 A load
        if (t + 1 < NITER) loadB(t + 1, bh0n, bl0n, bh1n, bl1n);
        if (t + 2 < NITER) cvtWrite(sc, t + 2);   // regs issued 2 iters ago
        compute(t);
        sc = sm; sm = sn;                         // rotate A slots
        bh0c = bh0n; bl0c = bl0n; bh1c = bh1n; bl1c = bl1n;
    }
    __syncthreads();

    // ---- merge K-halves: h=1 waves write partial, h=0 adds ----
    float* mg  = (float*)(smem + 32768);   // [32][128]
    if (h == 1) {
        #pragma unroll
        for (int r = 0; r < 16; ++r) {
            float cv = fmaf(acc2[r], 0.015625f, acc1[r]);
            int row = (r & 3) + 8 * (r >> 2) + 4 * (l >> 5);
            int col = f * 32 + (l & 31);
            mg[row * 128 + col] = cv;
        }
    }
    __syncthreads();

    float* lgf = (float*)smem;             // [32][132]
    if (h == 0) {
        #pragma unroll
        for (int r = 0; r < 16; ++r) {
            float cv = fmaf(acc2[r], 0.015625f, acc1[r]);
            int row = (r & 3) + 8 * (r >> 2) + 4 * (l >> 5);
            int col = f * 32 + (l & 31);
            lgf[row * 132 + col] = cv + mg[row * 128 + col];
        }
    }
    __syncthreads();

    // ---- phase1: noise injection; 512 thr = 32 rows x 16 float4-chunks ----
    {
        const int pr = tid & 31;           // row
        const int c4 = tid >> 5;           // float4 chunk 0..15
        const int n1 = row0 + pr;
        float4 G  = *(const float4*)(lgf + pr * 132 + c4 * 4);
        float4 NL = *(const float4*)(lgf + pr * 132 + 64 + c4 * 4);
        float4 NZ = *(const float4*)(noise + (size_t)n1 * NE + c4 * 4);
        G.x += NZ.x * softplus_f(NL.x) * NSCALE;
        G.y += NZ.y * softplus_f(NL.y) * NSCALE;
        G.z += NZ.z * softplus_f(NL.z) * NSCALE;
        G.w += NZ.w * softplus_f(NL.w) * NSCALE;
        *(float4*)(lgf + pr * 132 + c4 * 4) = G;
        *(float4*)(out_logits + (size_t)n1 * NE + c4 * 4) = G;
    }
    __syncthreads();

    // ---- phase2: per-row top-2 + softmax; waves 0..3, 8 lanes/row ----
    if (w < 4) {
        const int g2   = l >> 3;           // row within wave's 8-row group
        const int c    = l & 7;            // expert chunk of 8
        const int row2 = w * 8 + g2;
        const int n2   = row0 + row2;

        float mv[8];
        {
            const float4* mr = (const float4*)(lgf + row2 * 132 + c * 8);
            float4 m0 = mr[0], m1 = mr[1];
            mv[0]=m0.x; mv[1]=m0.y; mv[2]=m0.z; mv[3]=m0.w;
            mv[4]=m1.x; mv[5]=m1.y; mv[6]=m1.z; mv[7]=m1.w;
        }
        float v0 = -INFINITY, v1 = -INFINITY;
        int i0 = 0, i1 = 0;
        #pragma unroll
        for (int j = 0; j < 8; ++j) {
            float v = mv[j]; int e = c * 8 + j;
            if (v > v0) { v1 = v0; i1 = i0; v0 = v; i0 = e; }
            else if (v > v1) { v1 = v; i1 = e; }
        }
        #pragma unroll
        for (int m = 1; m <= 4; m <<= 1) {
            float ov0 = __shfl_xor(v0, m), ov1 = __shfl_xor(v1, m);
            int   oi0 = __shfl_xor(i0, m), oi1 = __shfl_xor(i1, m);
            if (ov0 > v0) {
                bool keep = (v0 > ov1);
                v1 = keep ? v0 : ov1; i1 = keep ? i0 : oi1;
                v0 = ov0; i0 = oi0;
            } else if (ov0 > v1) {
                v1 = ov0; i1 = oi0;
            }
        }
        const int srcl = l & 56;
        v0 = __shfl(v0, srcl); i0 = __shfl(i0, srcl);
        v1 = __shfl(v1, srcl); i1 = __shfl(i1, srcl);

        float se = 0.0f;
        #pragma unroll
        for (int j = 0; j < 8; ++j) se += expf(mv[j] - v0);
        se += __shfl_xor(se, 1); se += __shfl_xor(se, 2); se += __shfl_xor(se, 4);
        float inv_se = 1.0f / se;

        float t  = expf(v1 - v0);
        float w0 = 1.0f / (1.0f + t);
        float w1 = t * w0;

        float pr[8], wt[8];
        #pragma unroll
        for (int j = 0; j < 8; ++j) {
            int e = c * 8 + j;
            pr[j] = expf(mv[j] - v0) * inv_se;
            wt[j] = (e == i0) ? w0 : ((e == i1) ? w1 : 0.0f);
        }
        *(float4*)(out_probs + (size_t)n2 * NE + c * 8)     = make_float4(pr[0], pr[1], pr[2], pr[3]);
        *(float4*)(out_probs + (size_t)n2 * NE + c * 8 + 4) = make_float4(pr[4], pr[5], pr[6], pr[7]);
        *(float4*)(out_w + (size_t)n2 * NE + c * 8)         = make_float4(wt[0], wt[1], wt[2], wt[3]);
        *(float4*)(out_w + (size_t)n2 * NE + c * 8 + 4)     = make_float4(wt[4], wt[5], wt[6], wt[7]);
        if (c == 0) {
            *(float2*)(out_idx + (size_t)n2 * 2) = make_float2((float)i0, (float)i1);
        }
    }
}

extern "C" void kernel_launch(void* const* d_in, const int* in_sizes, int n_in,
                              void* d_out, int out_size, void* d_ws, size_t ws_size,
                              hipStream_t stream) {
    (void)in_sizes; (void)n_in; (void)ws_size; (void)out_size;
    const float* x     = (const float*)d_in[0];
    const float* Wg    = (const float*)d_in[1];
    const float* Wn    = (const float*)d_in[2];
    const float* noise = (const float*)d_in[3];
    float* out        = (float*)d_out;
    float* out_w      = out;
    float* out_idx    = out + (size_t)NROWS * NE;
    float* out_logits = out_idx + (size_t)NROWS * 2;
    float* out_probs  = out_logits + (size_t)NROWS * NE;
    f16* wfrag = (f16*)d_ws;   // 1 MB

    wprep_kernel<<<128, 256, 0, stream>>>(Wg, Wn, wfrag);
    gemm_gating<<<NROWS / BM, 512, 0, stream>>>(
        x, wfrag, noise, out_w, out_idx, out_logits, out_probs);
}